// Round 1
// 296.985 us; speedup vs baseline: 1.0551x; 1.0551x over previous
//
#include <hip/hip_runtime.h>

// GRU autoregressive decoder, bf16-MFMA persistent-weight, 8-wave blocks.
// B=16384, I=32, H=128, 30 steps, x0 = x[:,30,:], y feeds back as x.
//
// Round 4 -> 5 changes:
//  * BM 64->32, grid 256->512: 2 blocks/CU (4 waves/SIMD, occupancy 22->44%).
//    Blocks are independent, so one block's activation math overlaps the
//    other's barriers/MFMA -- fills the 37% stall the counters showed.
//  * sigm/tanh via __builtin_amdgcn_rcpf: kills the ~10-inst IEEE divide
//    sequence (no fast-math in harness flags) -> ~40% fewer VALU insts/step.
//    v_rcp_f32 is ~1ulp, far below the bf16 noise floor (absmax 0.0078).
//  * HBS 144->136: row stride 272B == 68 dwords == 4 (mod 32), quad stride
//    == 16 (mod 32) -> scalar h' b16 writes drop from 4-way to 2-way (free)
//    bank aliasing. 272B rows stay 16B-aligned for ds_read_b128.
//
// Wave w owns hidden units [16w,16w+16) -> persistent MFMA B-fragments
// (15 bf16x8 = 60 VGPR). h-state is lane-private fp32. bf16 h/x copies
// round-trip LDS only for the A-operand layout transform.
//
// GEMM1 per step: G[32x384] = [h|x][32x160] @ W'^T (K fused for r/z; n-gate
// keeps separate h/x accumulators since n = tanh(i_n + r*h_n)).
// GEMM2: y[32x32] = h'[32x128] @ Wout^T + bout; waves 0..3 each compute one
// 16x16 tile (rowtile=w>>1, coltile=w&1); waves 4..7 idle through phase 2.

#define NB    16384
#define TT    60
#define II    32
#define HH    128
#define NSTEP 30
#define SEQ0  30
#define BM    32
#define HBS   136   // bf16 h-row stride: 272B rows (68 dwords, 68%32=4)
#define XBS   40    // bf16 x-row stride: 80B rows

typedef __attribute__((ext_vector_type(8))) short bf16x8;
typedef __attribute__((ext_vector_type(4))) float f32x4;

#define MFMA(a, b, c) __builtin_amdgcn_mfma_f32_16x16x32_bf16((a), (b), (c), 0, 0, 0)

__device__ __forceinline__ short f2bf(float x) {  // RNE fp32->bf16
    unsigned u = __float_as_uint(x);
    u += 0x7FFFu + ((u >> 16) & 1u);
    return (short)(u >> 16);
}
__device__ __forceinline__ bf16x8 ldw8(const float* p) {  // 8 fp32 -> bf16x8
    float4 a = *(const float4*)p;
    float4 b = *(const float4*)(p + 4);
    bf16x8 f;
    f[0] = f2bf(a.x); f[1] = f2bf(a.y); f[2] = f2bf(a.z); f[3] = f2bf(a.w);
    f[4] = f2bf(b.x); f[5] = f2bf(b.y); f[6] = f2bf(b.z); f[7] = f2bf(b.w);
    return f;
}
// v_rcp_f32-based activations: 1 inst instead of the ~10-inst IEEE divide.
__device__ __forceinline__ float sigm(float a) {
    return __builtin_amdgcn_rcpf(1.0f + __expf(-a));
}
__device__ __forceinline__ float tanh_(float a) {
    return 1.0f - 2.0f * __builtin_amdgcn_rcpf(1.0f + __expf(2.0f * a));
}

__global__ __launch_bounds__(512, 4)
void gru_mfma_kernel(const float* __restrict__ x,
                     const float* __restrict__ h0,
                     const float* __restrict__ Wih,
                     const float* __restrict__ Whh,
                     const float* __restrict__ bih,
                     const float* __restrict__ bhh,
                     const float* __restrict__ Wout,
                     const float* __restrict__ bout,
                     float* __restrict__ out)
{
    __shared__ short shb[2][BM * HBS];  // bf16 h, double-buffered (17.4 KB)
    __shared__ short sxb[BM * XBS];     // bf16 x/y feedback (2.5 KB)

    const int tid    = threadIdx.x;
    const int lane   = tid & 63;
    const int wave   = __builtin_amdgcn_readfirstlane(tid >> 6);  // 0..7
    const int n16    = lane & 15;   // MFMA col / A-row index
    const int quad   = lane >> 4;   // MFMA k-group / D-row group
    const int rowblk = blockIdx.x * BM;

    // ---- persistent gate-weight B-fragments: wave w owns units [16w,16w+16)
    //      lane n16 holds W'[col=16w+n16][k = kt*32 + quad*8 .. +8) ----
    bf16x8 Br[5], Bz[5], Bnh[4], Bnx;
    float  b_r, b_z, b_nh, b_nx;
    {
        const int j = wave * 16 + n16;            // hidden unit (gate col)
        const float* wr = Whh + (size_t)j * HH;
        const float* wz = Whh + (size_t)(HH + j) * HH;
        const float* wn = Whh + (size_t)(2 * HH + j) * HH;
        #pragma unroll
        for (int kt = 0; kt < 4; ++kt) {
            Br[kt]  = ldw8(wr + kt * 32 + quad * 8);
            Bz[kt]  = ldw8(wz + kt * 32 + quad * 8);
            Bnh[kt] = ldw8(wn + kt * 32 + quad * 8);
        }
        Br[4] = ldw8(Wih + (size_t)j * II + quad * 8);
        Bz[4] = ldw8(Wih + (size_t)(HH + j) * II + quad * 8);
        Bnx   = ldw8(Wih + (size_t)(2 * HH + j) * II + quad * 8);
        b_r  = bih[j] + bhh[j];
        b_z  = bih[HH + j] + bhh[HH + j];
        b_nh = bhh[2 * HH + j];
        b_nx = bih[2 * HH + j];
    }
    // ---- phase-2 tile assignment + Wout column-tile (waves 0..3 only) ----
    const int rowtile = wave >> 1;    // 0/1: which 16 rows of the 32
    const int coltile = wave & 1;     // 0/1: which 16 output cols
    bf16x8 Bo[4];
    float  b_o = 0.0f;
    if (wave < 4) {
        const int i = coltile * 16 + n16;
        #pragma unroll
        for (int kt = 0; kt < 4; ++kt)
            Bo[kt] = ldw8(Wout + (size_t)i * HH + kt * 32 + quad * 8);
        b_o = bout[i];
    }

    // ---- lane-private fp32 h-state: slot (mt,reg) = h[row][col],
    //      row = mt*16 + quad*4 + reg, col = wave*16 + n16 ----
    float hst[2][4];
    {
        const int col = wave * 16 + n16;
        #pragma unroll
        for (int mt = 0; mt < 2; ++mt)
            #pragma unroll
            for (int reg = 0; reg < 4; ++reg)
                hst[mt][reg] = h0[(size_t)(rowblk + mt * 16 + quad * 4 + reg) * HH + col];
    }

    // ---- stage bf16 h0 and x0 into LDS (one-time, cooperative) ----
    {
        const int r  = tid >> 4;            // 32 rows, 16 threads/row
        const int c0 = (tid & 15) * 8;      // 8 cols each
        *(bf16x8*)&shb[0][r * HBS + c0] = ldw8(h0 + (size_t)(rowblk + r) * HH + c0);
    }
    if (tid < 128) {
        const int r  = tid >> 2;            // 32 rows, 4 threads/row
        const int c0 = (tid & 3) * 8;
        *(bf16x8*)&sxb[r * XBS + c0] = ldw8(x + ((size_t)(rowblk + r) * TT + SEQ0) * II + c0);
    }
    __syncthreads();

    const int colw = wave * 16 + n16;
    int p = 0;
    for (int s = 0; s < NSTEP; ++s) {
        // ==== phase 1: gates + h update (wave w: all 32 rows x its 16 units)
        #pragma unroll
        for (int mt = 0; mt < 2; ++mt) {
            bf16x8 A[5];   // A[m=n16][k=quad*8+j]; K-tiles: 4 from h, 1 from x
            #pragma unroll
            for (int kt = 0; kt < 4; ++kt)
                A[kt] = *(const bf16x8*)&shb[p][(mt * 16 + n16) * HBS + kt * 32 + quad * 8];
            A[4] = *(const bf16x8*)&sxb[(mt * 16 + n16) * XBS + quad * 8];

            f32x4 ar  = (f32x4){b_r,  b_r,  b_r,  b_r};
            f32x4 az  = (f32x4){b_z,  b_z,  b_z,  b_z};
            f32x4 anh = (f32x4){b_nh, b_nh, b_nh, b_nh};
            f32x4 anx = (f32x4){b_nx, b_nx, b_nx, b_nx};
            #pragma unroll
            for (int kt = 0; kt < 4; ++kt) {       // 3 indep acc chains per kt
                ar  = MFMA(A[kt], Br[kt],  ar);
                az  = MFMA(A[kt], Bz[kt],  az);
                anh = MFMA(A[kt], Bnh[kt], anh);
            }
            ar  = MFMA(A[4], Br[4], ar);           // x-part (K-tile 4)
            az  = MFMA(A[4], Bz[4], az);
            anx = MFMA(A[4], Bnx,   anx);

            // gates: D-layout col = wave*16+n16, row = mt*16 + quad*4 + reg
            #pragma unroll
            for (int reg = 0; reg < 4; ++reg) {
                const float r = sigm(ar[reg]);
                const float z = sigm(az[reg]);
                const float n = tanh_(anx[reg] + r * anh[reg]);
                const float hnew = n + z * (hst[mt][reg] - n);
                hst[mt][reg] = hnew;
                shb[1 - p][(mt * 16 + quad * 4 + reg) * HBS + colw] = f2bf(hnew);
            }
        }
        __syncthreads();   // h' visible to all waves; phase-1 x reads done

        // ==== phase 2: y = h' @ Wout^T + bout; waves 0..3, one 16x16 tile
        if (wave < 4) {
            bf16x8 A2[4];
            #pragma unroll
            for (int kt = 0; kt < 4; ++kt)
                A2[kt] = *(const bf16x8*)&shb[1 - p][(rowtile * 16 + n16) * HBS + kt * 32 + quad * 8];
            f32x4 yo = (f32x4){b_o, b_o, b_o, b_o};
            #pragma unroll
            for (int kt = 0; kt < 4; ++kt)
                yo = MFMA(A2[kt], Bo[kt], yo);
            #pragma unroll
            for (int reg = 0; reg < 4; ++reg) {
                const int r_l = rowtile * 16 + quad * 4 + reg;
                const float yv = yo[reg];
                out[(size_t)(rowblk + r_l) * (NSTEP * II) + s * II + coltile * 16 + n16] = yv;
                sxb[r_l * XBS + coltile * 16 + n16] = f2bf(yv);  // y -> next x
            }
        }
        p ^= 1;
        __syncthreads();   // sxb/shb visible before next step's phase-1 reads
    }
}

extern "C" void kernel_launch(void* const* d_in, const int* in_sizes, int n_in,
                              void* d_out, int out_size, void* d_ws, size_t ws_size,
                              hipStream_t stream) {
    (void)in_sizes; (void)n_in; (void)out_size; (void)d_ws; (void)ws_size;
    const float* x    = (const float*)d_in[0];
    const float* h0   = (const float*)d_in[1];
    const float* Wih  = (const float*)d_in[2];
    const float* Whh  = (const float*)d_in[3];
    const float* bih  = (const float*)d_in[4];
    const float* bhh  = (const float*)d_in[5];
    const float* Wout = (const float*)d_in[6];
    const float* bout = (const float*)d_in[7];
    float* out = (float*)d_out;

    dim3 grid(NB / BM);   // 512 blocks -> 2 per CU (16 waves = 4 waves/SIMD)
    dim3 block(512);
    gru_mfma_kernel<<<grid, block, 0, stream>>>(x, h0, Wih, Whh, bih, bhh,
                                                Wout, bout, out);
}

// Round 2
// 268.522 us; speedup vs baseline: 1.1669x; 1.1060x over previous
//
#include <hip/hip_runtime.h>

// GRU autoregressive decoder, bf16-MFMA persistent-weight, 8-wave blocks.
// B=16384, I=32, H=128, 30 steps, x0 = x[:,30,:], y feeds back as x.
//
// Round 5 -> 6 changes (fold the output projection into the recurrence):
//  * For steps >= 1, x_t = y_{t-1} = h*Wout^T + bout, so the x-GEMM folds:
//      pre_r = h @ (Whh_r + Wih_r*Wout)^T + (bih_r + bhh_r + Wih_r*bout)
//    (same for z; n-gate keeps i_n/h_n separate, i_n = h @ (Wih_n*Wout)^T).
//    A tiny prep kernel computes the folded W*/b* into d_ws (stream-ordered).
//  * ONE barrier per step (was 2): the only hazard left is the h' all-to-all
//    exchange. Phase 2 (y proj + store) runs AFTER the barrier reading the
//    just-written buffer while next step's phase 1 writes the other buffer —
//    race-free without a second __syncthreads, and it fills phase-1's shadow.
//  * sxb feedback write + its f2bf disappear (sxb used only for peeled step 0,
//    which uses the original un-folded weights + real x0).
//  * Back to BM=64 / 256 blocks / __launch_bounds__(512,2): round 5's
//    (512,4) squeezed the persistent fragments into 64 arch VGPRs and spilled
//    (FETCH 6->49MB, WRITE 63->157MB). 256-reg budget holds them clean.
//  * Keeps round 5's rcp-based activations (v_rcp_f32 vs 10-inst IEEE div).
//
// GEMM1 per step (s>=1): 4 K-tiles x {r,z,nh,ni} = 16 MFMA per m-tile.
// GEMM2: y[64x32] = h'[64x128] @ Wout^T + bout; wave w computes the
// (w>>1, w&1) 16x16 tile and holds only its own Wout column-tile.

#define NB    16384
#define TT    60
#define II    32
#define HH    128
#define NSTEP 30
#define SEQ0  30
#define BM    64
#define HBS   136   // bf16 h-row stride: 272B rows (68 dwords, 68%32=4)
#define XBS   40    // bf16 x-row stride: 80B rows (step-0 x0 only)

// d_ws layout (floats): Wstar[384][128] at 0, bstar[384] at 49152.
#define WS_WSTAR 0
#define WS_BSTAR (384 * 128)

typedef __attribute__((ext_vector_type(8))) short bf16x8;
typedef __attribute__((ext_vector_type(4))) float f32x4;

#define MFMA(a, b, c) __builtin_amdgcn_mfma_f32_16x16x32_bf16((a), (b), (c), 0, 0, 0)

__device__ __forceinline__ short f2bf(float x) {  // RNE fp32->bf16
    unsigned u = __float_as_uint(x);
    u += 0x7FFFu + ((u >> 16) & 1u);
    return (short)(u >> 16);
}
__device__ __forceinline__ bf16x8 ldw8(const float* p) {  // 8 fp32 -> bf16x8
    float4 a = *(const float4*)p;
    float4 b = *(const float4*)(p + 4);
    bf16x8 f;
    f[0] = f2bf(a.x); f[1] = f2bf(a.y); f[2] = f2bf(a.z); f[3] = f2bf(a.w);
    f[4] = f2bf(b.x); f[5] = f2bf(b.y); f[6] = f2bf(b.z); f[7] = f2bf(b.w);
    return f;
}
// v_rcp_f32-based activations: 1 inst instead of the ~10-inst IEEE divide.
__device__ __forceinline__ float sigm(float a) {
    return __builtin_amdgcn_rcpf(1.0f + __expf(-a));
}
__device__ __forceinline__ float tanh_(float a) {
    return 1.0f - 2.0f * __builtin_amdgcn_rcpf(1.0f + __expf(2.0f * a));
}

// ---- prep: Wstar[jg][k] = (gate<2 ? Whh[jg][k] : 0) + sum_i Wih[jg][i]*Wout[i][k]
//      bstar[jg]  = bih[jg] + (gate<2 ? bhh[jg] : 0) + sum_i Wih[jg][i]*bout[i]
// (n-gate keeps bhh_n / Whh_n separate in the main kernel's h_n accumulator.)
__global__ void fold_kernel(const float* __restrict__ Wih,
                            const float* __restrict__ Whh,
                            const float* __restrict__ bih,
                            const float* __restrict__ bhh,
                            const float* __restrict__ Wout,
                            const float* __restrict__ bout,
                            float* __restrict__ ws)
{
    const int jg = blockIdx.x;     // 0..383 = gate*128 + j
    const int k  = threadIdx.x;    // 0..127
    const int gate = jg >> 7;
    float acc  = (gate < 2) ? Whh[(size_t)jg * HH + k] : 0.0f;
    float bacc = 0.0f;
    #pragma unroll 8
    for (int i = 0; i < II; ++i) {
        const float w = Wih[(size_t)jg * II + i];
        acc  += w * Wout[(size_t)i * HH + k];
        bacc += w * bout[i];
    }
    ws[WS_WSTAR + (size_t)jg * HH + k] = acc;
    if (k == 0)
        ws[WS_BSTAR + jg] = bih[jg] + ((gate < 2) ? bhh[jg] : 0.0f) + bacc;
}

__global__ __launch_bounds__(512, 2)
void gru_mfma_kernel(const float* __restrict__ x,
                     const float* __restrict__ h0,
                     const float* __restrict__ Wih,
                     const float* __restrict__ Whh,
                     const float* __restrict__ bih,
                     const float* __restrict__ bhh,
                     const float* __restrict__ Wout,
                     const float* __restrict__ bout,
                     const float* __restrict__ ws,
                     float* __restrict__ out)
{
    __shared__ short shb[2][BM * HBS];  // bf16 h, double-buffered (34.8 KB)
    __shared__ short sxb[BM * XBS];     // bf16 x0 (step 0 only, 5.1 KB)

    const int tid    = threadIdx.x;
    const int lane   = tid & 63;
    const int wave   = __builtin_amdgcn_readfirstlane(tid >> 6);  // 0..7
    const int n16    = lane & 15;   // MFMA col / A-row index
    const int quad   = lane >> 4;   // MFMA k-group / D-row group
    const int rowblk = blockIdx.x * BM;
    const int j      = wave * 16 + n16;   // hidden unit this lane's gate col

    // ---- persistent n-gate h-weights (used by ALL steps) ----
    bf16x8 Bnh[4];
    float  b_nh;
    {
        const float* wn = Whh + (size_t)(2 * HH + j) * HH;
        #pragma unroll
        for (int kt = 0; kt < 4; ++kt)
            Bnh[kt] = ldw8(wn + kt * 32 + quad * 8);
        b_nh = bhh[2 * HH + j];
    }
    // ---- phase-2 tile assignment + this wave's Wout column-tile ----
    const int rowtile = wave >> 1;    // 0..3: which 16 rows of the 64
    const int coltile = wave & 1;     // 0/1:  which 16 output cols
    bf16x8 Bo[4];
    float  b_o;
    {
        const int i = coltile * 16 + n16;
        #pragma unroll
        for (int kt = 0; kt < 4; ++kt)
            Bo[kt] = ldw8(Wout + (size_t)i * HH + kt * 32 + quad * 8);
        b_o = bout[i];
    }

    // ---- lane-private fp32 h-state: slot (mt,reg) = h[row][col],
    //      row = mt*16 + quad*4 + reg, col = wave*16 + n16 ----
    float hst[4][4];
    #pragma unroll
    for (int mt = 0; mt < 4; ++mt)
        #pragma unroll
        for (int reg = 0; reg < 4; ++reg)
            hst[mt][reg] = h0[(size_t)(rowblk + mt * 16 + quad * 4 + reg) * HH + j];

    // ---- stage bf16 h0 and x0 into LDS (one-time, cooperative) ----
    {
        const int r  = tid >> 3;            // 64 rows, 8 threads/row
        const int c0 = (tid & 7) * 16;      // 16 cols each
        const float* src = h0 + (size_t)(rowblk + r) * HH + c0;
        *(bf16x8*)&shb[0][r * HBS + c0]     = ldw8(src);
        *(bf16x8*)&shb[0][r * HBS + c0 + 8] = ldw8(src + 8);
    }
    if (tid < 256) {
        const int r  = tid >> 2;            // 64 rows, 4 threads/row
        const int c0 = (tid & 3) * 8;
        const float* src = x + ((size_t)(rowblk + r) * TT + SEQ0) * II + c0;
        *(bf16x8*)&sxb[r * XBS + c0] = ldw8(src);
    }
    __syncthreads();

    // ================= peeled step 0: un-folded weights + real x0 =========
    {
        // transient step-0 weights: plain Whh for r/z + Wih K=32 tiles
        bf16x8 Br0[4], Bz0[4], Bxr, Bxz, Bxn;
        const float* wr = Whh + (size_t)j * HH;
        const float* wz = Whh + (size_t)(HH + j) * HH;
        #pragma unroll
        for (int kt = 0; kt < 4; ++kt) {
            Br0[kt] = ldw8(wr + kt * 32 + quad * 8);
            Bz0[kt] = ldw8(wz + kt * 32 + quad * 8);
        }
        Bxr = ldw8(Wih + (size_t)j * II + quad * 8);
        Bxz = ldw8(Wih + (size_t)(HH + j) * II + quad * 8);
        Bxn = ldw8(Wih + (size_t)(2 * HH + j) * II + quad * 8);
        const float b_r0 = bih[j] + bhh[j];
        const float b_z0 = bih[HH + j] + bhh[HH + j];
        const float b_n0 = bih[2 * HH + j];

        #pragma unroll
        for (int mt = 0; mt < 4; ++mt) {
            bf16x8 A[4], Ax;
            #pragma unroll
            for (int kt = 0; kt < 4; ++kt)
                A[kt] = *(const bf16x8*)&shb[0][(mt * 16 + n16) * HBS + kt * 32 + quad * 8];
            Ax = *(const bf16x8*)&sxb[(mt * 16 + n16) * XBS + quad * 8];

            f32x4 ar  = (f32x4){b_r0, b_r0, b_r0, b_r0};
            f32x4 az  = (f32x4){b_z0, b_z0, b_z0, b_z0};
            f32x4 anh = (f32x4){b_nh, b_nh, b_nh, b_nh};
            f32x4 anx = (f32x4){b_n0, b_n0, b_n0, b_n0};
            #pragma unroll
            for (int kt = 0; kt < 4; ++kt) {
                ar  = MFMA(A[kt], Br0[kt], ar);
                az  = MFMA(A[kt], Bz0[kt], az);
                anh = MFMA(A[kt], Bnh[kt], anh);
            }
            ar  = MFMA(Ax, Bxr, ar);
            az  = MFMA(Ax, Bxz, az);
            anx = MFMA(Ax, Bxn, anx);

            #pragma unroll
            for (int reg = 0; reg < 4; ++reg) {
                const float r = sigm(ar[reg]);
                const float z = sigm(az[reg]);
                const float n = tanh_(anx[reg] + r * anh[reg]);
                const float hnew = n + z * (hst[mt][reg] - n);
                hst[mt][reg] = hnew;
                shb[1][(mt * 16 + quad * 4 + reg) * HBS + j] = f2bf(hnew);
            }
        }
    }

    // ---- folded steady-state weights (from ws; dead step-0 regs reused) ----
    bf16x8 Brs[4], Bzs[4], Bni[4];
    float  b_rs, b_zs, b_ni;
    {
        const float* pr = ws + WS_WSTAR + (size_t)j * HH;
        const float* pz = ws + WS_WSTAR + (size_t)(HH + j) * HH;
        const float* pn = ws + WS_WSTAR + (size_t)(2 * HH + j) * HH;
        #pragma unroll
        for (int kt = 0; kt < 4; ++kt) {
            Brs[kt] = ldw8(pr + kt * 32 + quad * 8);
            Bzs[kt] = ldw8(pz + kt * 32 + quad * 8);
            Bni[kt] = ldw8(pn + kt * 32 + quad * 8);
        }
        b_rs = ws[WS_BSTAR + j];
        b_zs = ws[WS_BSTAR + HH + j];
        b_ni = ws[WS_BSTAR + 2 * HH + j];
    }

    __syncthreads();   // step-0 h' visible to all waves

    // ================= steps 0..29: {phase2(s) || phase1(s+1)} =============
    // Invariant at loop top: barrier for step s passed; shb[q] holds h_{s+1}
    // (q = 1 - p). Phase 2 of step s reads shb[q]; phase 1 of step s+1 reads
    // shb[q] and writes shb[p] — disjoint, so no barrier in between.
    int p = 0;
    for (int s = 0; s < NSTEP; ++s) {
        const int q = 1 - p;

        // ---- phase 2 of step s: y = h_{s+1} @ Wout^T + bout ----
        {
            bf16x8 A2[4];
            #pragma unroll
            for (int kt = 0; kt < 4; ++kt)
                A2[kt] = *(const bf16x8*)&shb[q][(rowtile * 16 + n16) * HBS + kt * 32 + quad * 8];
            f32x4 yo = (f32x4){b_o, b_o, b_o, b_o};
            #pragma unroll
            for (int kt = 0; kt < 4; ++kt)
                yo = MFMA(A2[kt], Bo[kt], yo);
            #pragma unroll
            for (int reg = 0; reg < 4; ++reg) {
                const int r_l = rowtile * 16 + quad * 4 + reg;
                out[(size_t)(rowblk + r_l) * (NSTEP * II) + s * II + coltile * 16 + n16] = yo[reg];
            }
        }

        if (s == NSTEP - 1) break;   // last y written; no more recurrence

        // ---- phase 1 of step s+1: gates + h update (folded, K=128 only) ----
        #pragma unroll
        for (int mt = 0; mt < 4; ++mt) {
            bf16x8 A[4];
            #pragma unroll
            for (int kt = 0; kt < 4; ++kt)
                A[kt] = *(const bf16x8*)&shb[q][(mt * 16 + n16) * HBS + kt * 32 + quad * 8];

            f32x4 ar  = (f32x4){b_rs, b_rs, b_rs, b_rs};
            f32x4 az  = (f32x4){b_zs, b_zs, b_zs, b_zs};
            f32x4 anh = (f32x4){b_nh, b_nh, b_nh, b_nh};
            f32x4 ani = (f32x4){b_ni, b_ni, b_ni, b_ni};
            #pragma unroll
            for (int kt = 0; kt < 4; ++kt) {       // 4 indep acc chains
                ar  = MFMA(A[kt], Brs[kt], ar);
                az  = MFMA(A[kt], Bzs[kt], az);
                anh = MFMA(A[kt], Bnh[kt], anh);
                ani = MFMA(A[kt], Bni[kt], ani);
            }

            #pragma unroll
            for (int reg = 0; reg < 4; ++reg) {
                const float r = sigm(ar[reg]);
                const float z = sigm(az[reg]);
                const float n = tanh_(ani[reg] + r * anh[reg]);
                const float hnew = n + z * (hst[mt][reg] - n);
                hst[mt][reg] = hnew;
                shb[p][(mt * 16 + quad * 4 + reg) * HBS + j] = f2bf(hnew);
            }
        }

        p = q;             // next step reads the buffer just written
        __syncthreads();   // ONE barrier per step: h' exchange
    }
}

extern "C" void kernel_launch(void* const* d_in, const int* in_sizes, int n_in,
                              void* d_out, int out_size, void* d_ws, size_t ws_size,
                              hipStream_t stream) {
    (void)in_sizes; (void)n_in; (void)out_size; (void)ws_size;
    const float* x    = (const float*)d_in[0];
    const float* h0   = (const float*)d_in[1];
    const float* Wih  = (const float*)d_in[2];
    const float* Whh  = (const float*)d_in[3];
    const float* bih  = (const float*)d_in[4];
    const float* bhh  = (const float*)d_in[5];
    const float* Wout = (const float*)d_in[6];
    const float* bout = (const float*)d_in[7];
    float* out = (float*)d_out;
    float* ws  = (float*)d_ws;

    fold_kernel<<<dim3(384), dim3(128), 0, stream>>>(Wih, Whh, bih, bhh,
                                                     Wout, bout, ws);
    dim3 grid(NB / BM);   // 256 blocks -> 1 per CU (8 waves = 2 waves/SIMD)
    dim3 block(512);
    gru_mfma_kernel<<<grid, block, 0, stream>>>(x, h0, Wih, Whh, bih, bhh,
                                                Wout, bout, ws, out);
}